// Round 9
// baseline (328.142 us; speedup 1.0000x reference)
//
#include <hip/hip_runtime.h>
#include <math.h>

#define H 1024
#define NH 16
#define HD 64
#define B_ 4
#define S_ 2048
#define ROWS (B_*S_)   // 8192

// -0.125 * log2(e): folded into Qh so sigmoid(s*0.125) = rcp(1 + exp2(dot))
#define QSCALE (-0.1803368801111664f)
#define ROPE_C (9.210340371976184f / 32.0f)   // ln(10000)/32

typedef __bf16 bf16x2_t __attribute__((ext_vector_type(2)));
typedef __bf16 bf16x4_t __attribute__((ext_vector_type(4)));
typedef __bf16 bf16x8_t __attribute__((ext_vector_type(8)));
typedef float floatx4_t __attribute__((ext_vector_type(4)));
typedef float floatx16_t __attribute__((ext_vector_type(16)));

// async global->LDS, 16B per lane, dest = wave-uniform base + lane*16
#define GLOAD_LDS16(gp, lp)                                                        \
    __builtin_amdgcn_global_load_lds(                                              \
        (const __attribute__((address_space(1))) unsigned int*)(gp),               \
        (__attribute__((address_space(3))) unsigned int*)(lp), 16, 0, 0)

// ---------------------------------------------------------------------------
// Fused prep: x->bf16 copy, Wp transpose+cvt, Wt transpose+cvt (one dispatch)
// ---------------------------------------------------------------------------
__global__ __launch_bounds__(256)
void prep_kernel(const float* __restrict__ x, const float* __restrict__ Wp,
                 const float* __restrict__ Wt,
                 __bf16* __restrict__ Ax, __bf16* __restrict__ Wp_t,
                 __bf16* __restrict__ Wt_t)
{
    __shared__ __bf16 t[32][33];
    const int flat = blockIdx.x;
    const int tid = threadIdx.x;

    if (flat < 8192) {
        size_t i = (size_t)flat * 256 + tid;
        float4 v = *reinterpret_cast<const float4*>(&x[i * 4]);
        bf16x4_t w = { (__bf16)v.x, (__bf16)v.y, (__bf16)v.z, (__bf16)v.w };
        *reinterpret_cast<bf16x4_t*>(&Ax[i * 4]) = w;
        return;
    }
    const float* W; __bf16* Wo; int K, N, bn, bk;
    if (flat < 12288) {
        int id = flat - 8192;  W = Wp; Wo = Wp_t; K = 1024; N = 4096;
        bn = (id & 127) * 32;  bk = (id >> 7) * 32;
    } else {
        int id = flat - 12288; W = Wt; Wo = Wt_t; K = 1024; N = 1024;
        bn = (id & 31) * 32;   bk = (id >> 5) * 32;
    }
    const int tx = tid & 31, ty = tid >> 5;
#pragma unroll
    for (int i = 0; i < 4; i++) {
        int r = ty + i * 8;
        t[tx][r] = (__bf16)W[(size_t)(bk + r) * N + bn + tx];
    }
    __syncthreads();
#pragma unroll
    for (int i = 0; i < 4; i++) {
        int r = ty + i * 8;
        Wo[(size_t)(bn + r) * K + bk + tx] = t[r][tx];
    }
}

// ===========================================================================
// gemm_proj (R1/R5 skeleton + R8 one-phase-lookahead ds_reads): 256x256 tile,
// BK=64, 8 waves (2M x 4N), 8-phase schedule, 16x16x32 MFMA, default x-major
// 2D grid (XCD swizzle rejected R4: FETCH 73.9->135MB).
//
// R8 delta: fragments for phase p+1 are ds_read during phase p (before the
// mid barrier) so LDS-read time hides under phase p's MFMA cluster — the
// 38% MfmaUtil plateau was read->barrier->MFMA serialization (~580cy LDS +
// ~620cy MFMA per phase, alternating). Register rotation (compile-time under
// full unroll): af slot = phase&1 (lifetime 1 phase), bfr slot = (phase>>1)&1
// (lifetime 2 phases). Safety audit vs UNCHANGED stage/vmcnt/barrier skeleton:
//  - validity: reads for p+1 issued at p target slots staged >=4 phases
//    earlier and load-guaranteed by the latest vmcnt(6) (buf-crossing reads
//    at p3/p7 are issued AFTER that phase's vmcnt);
//  - WAR: reads for phase q are lgkm-waited before q's MFMA < q's end
//    barrier; every slot's restage is >= 1 phase after its last consuming
//    phase (B[0][0]: consumed p0, staged p1; A[0][0]: consumed p0-p1, staged
//    p2; B[0][1]: p2-p3/p3; A[0][1]: p2-p3/p4; buf1 mirrors at p4-p7).
//  - final it=7,p7 lookahead reads clamped tile-15 junk; values unused.
// Stage table: p0 A[1][1]<-T+1 | p1 B[0][0]<-T+2 | p2 A[0][0]<-T+2
//              p3 B[0][1]<-T+2 | p4 A[0][1]<-T+2 | p5 B[1][0]<-T+3
//              p6 A[1][0]<-T+3 | p7 B[1][1]<-T+3   (T=2*iter)
// vmcnt(6) after stage at p3/p7 only. Swizzle: chunk c of row r at linear
// chunk c^((r>>1)&3) via inverse-permuted GLOBAL source (linear LDS dest).
// C/D layout 16x16 (m89/m91): col=lane&15, row=(lane>>4)*4+reg.
// ===========================================================================

#define MIN15(x) ((x) < 15 ? (x) : 15)

#define STAGE_A(buf, h, tile) do { int _kb = (tile) * 64 + (h) * 32;               \
        char* _lb = lwA + ((buf) * 2 + (h)) * 16384;                               \
        GLOAD_LDS16(a_src0 + _kb, _lb);                                            \
        GLOAD_LDS16(a_src1 + _kb, _lb + 1024); } while (0)
#define STAGE_B(buf, h, tile) do { int _kb = (tile) * 64 + (h) * 32;               \
        char* _lb = lwB + ((buf) * 2 + (h)) * 16384;                               \
        GLOAD_LDS16(b_src0 + _kb, _lb);                                            \
        GLOAD_LDS16(b_src1 + _kb, _lb + 1024); } while (0)

__global__ __launch_bounds__(512, 2)
void gemm_proj(const __bf16* __restrict__ A, const __bf16* __restrict__ Bt,
               const float* __restrict__ bias,
               __bf16* __restrict__ Ug, __bf16* __restrict__ Vh,
               __bf16* __restrict__ Qh, __bf16* __restrict__ Kh)
{
    __shared__ __attribute__((aligned(16))) char smem[131072];

    const int tid  = threadIdx.x;
    const int wave = tid >> 6, lane = tid & 63;
    const int ln15 = lane & 15, q4 = lane >> 4;
    const int wm = wave & 1, wn = wave >> 1;
    const int m0 = blockIdx.y * 256, n0 = blockIdx.x * 256;

    // ---- staging constants: linear LDS dest, inverse-swizzled global src ----
    const int srow0 = wave * 32 + (lane >> 2);            // row for load p=0
    const int csrc  = (lane & 3) ^ ((lane >> 3) & 3);     // swizzled 16B chunk
    const __bf16* a_src0 = A  + (size_t)(m0 + srow0) * 1024 + csrc * 8;
    const __bf16* a_src1 = a_src0 + (size_t)16 * 1024;    // row +16 (load p=1)
    const __bf16* b_src0 = Bt + (size_t)(n0 + srow0) * 1024 + csrc * 8;
    const __bf16* b_src1 = b_src0 + (size_t)16 * 1024;
    char* lwA = smem + wave * 2048;                       // + slot*16384
    char* lwB = smem + 65536 + wave * 2048;

    // ---- fragment read offsets (swizzled) ----
    const int sl = (ln15 >> 1) & 3;
    const int a_lane = (wm * 128 + ln15) * 64 + ((q4 ^ sl) << 4);
    const int b_lane = (wn * 64  + ln15) * 64 + ((q4 ^ sl) << 4);

    floatx4_t acc[8][4];
#pragma unroll
    for (int i = 0; i < 8; i++)
#pragma unroll
        for (int j = 0; j < 4; j++) acc[i][j] = (floatx4_t){0.f, 0.f, 0.f, 0.f};

    // ---- prologue: T0 all 4 halves + T1 {Bk0, Ak0, Bk1}, FIFO order ----
    STAGE_B(0, 0, 0); STAGE_A(0, 0, 0); STAGE_B(0, 1, 0); STAGE_A(0, 1, 0);
    STAGE_B(1, 0, 1); STAGE_A(1, 0, 1); STAGE_B(1, 1, 1);
    asm volatile("s_waitcnt vmcnt(6)" ::: "memory");   // buf0 (first 8 loads) landed
    __builtin_amdgcn_s_barrier();

    // ---- double fragment set: af slot = phase&1, bfr slot = (phase>>1)&1 ----
    bf16x8_t af_reg[2][4], bfr_reg[2][4];
    // pre-read phase-0 fragments (buf0, kk=0, mh=0) into slot 0
#pragma unroll
    for (int nf = 0; nf < 4; nf++)
        bfr_reg[0][nf] = *reinterpret_cast<const bf16x8_t*>(smem + 65536 + b_lane + nf * 1024);
#pragma unroll
    for (int mfi = 0; mfi < 4; mfi++)
        af_reg[0][mfi] = *reinterpret_cast<const bf16x8_t*>(smem + a_lane + mfi * 1024);

    for (int it = 0; it < 8; ++it) {
        const int T = 2 * it;
#pragma unroll
        for (int p = 0; p < 8; ++p) {
            const int cur = p & 1, bslot = (p >> 1) & 1;
            const int mh = p & 1;                        // sub&1 (acc half)
            // next-phase read targets
            const int np = (p + 1) & 7;
            const int nbuf = np >> 2, nsub = np & 3, nmh = nsub & 1, nkk = nsub >> 1;
            const char* nasl = smem + (nbuf * 2 + nkk) * 16384;
            const char* nbsl = smem + 65536 + (nbuf * 2 + nkk) * 16384;

            // stage one half-tile (unchanged schedule)
            if      (p == 0) STAGE_A(1, 1, MIN15(T + 1));
            else if (p == 1) STAGE_B(0, 0, MIN15(T + 2));
            else if (p == 2) STAGE_A(0, 0, MIN15(T + 2));
            else if (p == 3) STAGE_B(0, 1, MIN15(T + 2));
            else if (p == 4) STAGE_A(0, 1, MIN15(T + 2));
            else if (p == 5) STAGE_B(1, 0, MIN15(T + 3));
            else if (p == 6) STAGE_A(1, 0, MIN15(T + 3));
            else             STAGE_B(1, 1, MIN15(T + 3));

            if (p == 3 || p == 7)
                asm volatile("s_waitcnt vmcnt(6)" ::: "memory");

            // lookahead: read phase p+1's fragments now — they complete
            // under THIS phase's MFMA (compiler emits counted lgkmcnt).
            if ((nsub & 1) == 0) {
#pragma unroll
                for (int nf = 0; nf < 4; nf++)
                    bfr_reg[((p + 1) >> 1) & 1][nf] =
                        *reinterpret_cast<const bf16x8_t*>(nbsl + b_lane + nf * 1024);
            }
#pragma unroll
            for (int mfi = 0; mfi < 4; mfi++)
                af_reg[cur ^ 1][mfi] =
                    *reinterpret_cast<const bf16x8_t*>(nasl + a_lane + (nmh * 4 + mfi) * 1024);

            __builtin_amdgcn_s_barrier();

            __builtin_amdgcn_s_setprio(1);
#pragma unroll
            for (int nf = 0; nf < 4; nf++)
#pragma unroll
                for (int mfi = 0; mfi < 4; mfi++)
                    acc[mh * 4 + mfi][nf] = __builtin_amdgcn_mfma_f32_16x16x32_bf16(
                        af_reg[cur][mfi], bfr_reg[bslot][nf], acc[mh * 4 + mfi][nf], 0, 0, 0);
            __builtin_amdgcn_s_setprio(0);
            __builtin_amdgcn_s_barrier();
        }
    }
    asm volatile("s_waitcnt vmcnt(0)" ::: "memory");

    // ---- split epilogue (block-uniform region branch) ----
    const int colbase = n0 + wn * 64;
    float bv[4];
#pragma unroll
    for (int nf = 0; nf < 4; nf++) bv[nf] = bias[colbase + nf * 16 + ln15];

    const int rowb = m0 + wm * 128 + q4 * 4;   // + mf*16 + reg

    if (n0 < 1024) {
#pragma unroll
        for (int mf = 0; mf < 8; mf++)
#pragma unroll
            for (int nf = 0; nf < 4; nf++) {
                int col = colbase + nf * 16 + ln15;
#pragma unroll
                for (int reg = 0; reg < 4; reg++) {
                    int row = rowb + mf * 16 + reg;
                    Ug[(size_t)row * 1024 + col] = (__bf16)(acc[mf][nf][reg] + bv[nf]);
                }
            }
    } else if (n0 < 2048) {
        const int h = ((n0 - 1024) >> 6) + wn;    // wave spans one head
#pragma unroll
        for (int mf = 0; mf < 8; mf++)
#pragma unroll
            for (int reg = 0; reg < 4; reg++) {
                int row = rowb + mf * 16 + reg;
                int b = row >> 11, s = row & (S_ - 1);
                size_t orow = ((size_t)(b * NH + h) * S_ + s) * 64;
#pragma unroll
                for (int nf = 0; nf < 4; nf++)
                    Vh[orow + nf * 16 + ln15] = (__bf16)(acc[mf][nf][reg] + bv[nf]);
            }
    } else {
        const bool isQ = (n0 < 3072);
        const int h = ((n0 - (isQ ? 2048 : 3072)) >> 6) + wn;
        __bf16* dst = isQ ? Qh : Kh;
        const float sc = isQ ? QSCALE : 1.0f;
        // RoPE pair (d, d+32): d = nf*16+ln15 (nf=0,1), hi partner nf+2
        float inv[2];
        inv[0] = __expf(-(float)(ln15)      * ROPE_C);
        inv[1] = __expf(-(float)(16 + ln15) * ROPE_C);
#pragma unroll
        for (int mf = 0; mf < 8; mf++)
#pragma unroll
            for (int reg = 0; reg < 4; reg++) {
                int row = rowb + mf * 16 + reg;
                int b = row >> 11, s = row & (S_ - 1);
                size_t orow = ((size_t)(b * NH + h) * S_ + s) * 64;
#pragma unroll
                for (int nf = 0; nf < 2; nf++) {
                    float sn, cs;
                    __sincosf((float)s * inv[nf], &sn, &cs);
                    float lo = acc[mf][nf][reg]     + bv[nf];
                    float hi = acc[mf][nf + 2][reg] + bv[nf + 2];
                    int d = nf * 16 + ln15;
                    dst[orow + d]      = (__bf16)((lo * cs - hi * sn) * sc);
                    dst[orow + 32 + d] = (__bf16)((hi * cs + lo * sn) * sc);
                }
            }
    }
}

// ---------------------------------------------------------------------------
// out-proj GEMM: C = A @ Bt^T + bias + resid (fp32 out). 128x128, m97 struct.
// ---------------------------------------------------------------------------
__global__ __launch_bounds__(256)
void gemm_out(const __bf16* __restrict__ A, const __bf16* __restrict__ Bt,
              const float* __restrict__ bias, const float* __restrict__ resid,
              float* __restrict__ C, int M, int N, int K)
{
    __shared__ __bf16 As[128 * 32];
    __shared__ __bf16 Bs[128 * 32];

    const int tid  = threadIdx.x;
    const int wave = tid >> 6, lane = tid & 63;
    const int l31 = lane & 31, half = lane >> 5;
    const int wm = wave & 1, wn = wave >> 1;
    const int m0 = blockIdx.y * 128, n0 = blockIdx.x * 128;

    const int srow = lane >> 2;
    const int skc  = (((lane & 3) ^ ((srow >> 1) & 3)) * 8);

    const int fsw = (l31 >> 1) & 3;
    int aoff[2][2], boff[2][2];
#pragma unroll
    for (int mt = 0; mt < 2; mt++)
#pragma unroll
        for (int ks = 0; ks < 2; ks++) {
            int ra = wm * 64 + mt * 32 + l31;
            int rb = wn * 64 + mt * 32 + l31;
            int c = ks * 2 + half;
            aoff[mt][ks] = ra * 32 + ((c ^ fsw) * 8);
            boff[mt][ks] = rb * 32 + ((c ^ fsw) * 8);
        }

    floatx16_t acc[2][2];
#pragma unroll
    for (int i = 0; i < 2; i++)
#pragma unroll
        for (int j = 0; j < 2; j++) acc[i][j] = (floatx16_t)(0.f);

    for (int k0 = 0; k0 < K; k0 += 32) {
#pragma unroll
        for (int p = 0; p < 2; p++) {
            int i = wave * 2 + p;
            int rl = i * 16 + srow;
            GLOAD_LDS16(A  + (size_t)(m0 + rl) * K + k0 + skc, &As[i * 512]);
            GLOAD_LDS16(Bt + (size_t)(n0 + rl) * K + k0 + skc, &Bs[i * 512]);
        }
        __syncthreads();

        bf16x8_t af[2][2], bf[2][2];
#pragma unroll
        for (int mt = 0; mt < 2; mt++)
#pragma unroll
            for (int ks = 0; ks < 2; ks++) {
                af[mt][ks] = *reinterpret_cast<const bf16x8_t*>(&As[aoff[mt][ks]]);
                bf[mt][ks] = *reinterpret_cast<const bf16x8_t*>(&Bs[boff[mt][ks]]);
            }
#pragma unroll
        for (int ks = 0; ks < 2; ks++)
#pragma unroll
            for (int mt = 0; mt < 2; mt++)
#pragma unroll
                for (int nt = 0; nt < 2; nt++)
                    acc[mt][nt] = __builtin_amdgcn_mfma_f32_32x32x16_bf16(
                        af[mt][ks], bf[nt][ks], acc[mt][nt], 0, 0, 0);
        __syncthreads();
    }

#pragma unroll
    for (int mt = 0; mt < 2; mt++) {
#pragma unroll
        for (int nt = 0; nt < 2; nt++) {
            int col = n0 + wn * 64 + nt * 32 + l31;
            float bv = bias[col];
#pragma unroll
            for (int reg = 0; reg < 16; reg++) {
                int rowf = (reg & 3) + 8 * (reg >> 2) + 4 * half;
                int row = m0 + wm * 64 + mt * 32 + rowf;
                C[(size_t)row * N + col] = acc[mt][nt][reg] + bv + resid[(size_t)row * N + col];
            }
        }
    }
}

// ---------------------------------------------------------------------------
// V transpose: Vh[bh][s][64] -> VtG[bh][d][S]
// ---------------------------------------------------------------------------
__global__ __launch_bounds__(256)
void transpose_v(const __bf16* __restrict__ Vh, __bf16* __restrict__ VtG)
{
    const int tid = threadIdx.x;
    const int st = blockIdx.x, bh = blockIdx.y;
    const int s0 = st * 64;
    const int d = tid & 63, k16 = tid >> 6;
    __bf16 vals[16];
#pragma unroll
    for (int j = 0; j < 16; j++) {
        int k = s0 + k16 * 16 + j;
        vals[j] = Vh[((size_t)bh * S_ + k) * 64 + d];
    }
    size_t orow = ((size_t)(bh * 64 + d)) * S_ + s0 + k16 * 16;
    *reinterpret_cast<bf16x8_t*>(&VtG[orow])     = *reinterpret_cast<bf16x8_t*>(&vals[0]);
    *reinterpret_cast<bf16x8_t*>(&VtG[orow + 8]) = *reinterpret_cast<bf16x8_t*>(&vals[8]);
}

// ---------------------------------------------------------------------------
// Sigmoid attention, causal, bf16 MFMA. (R1 structure: 8 waves, one 16-row
// q-subtile per wave, qt-pairing for load balance; T5 setprio around QK/PV
// MFMA clusters.)
// ---------------------------------------------------------------------------
__global__ __launch_bounds__(512, 4)
void attn_mfma(const __bf16* __restrict__ Qh, const __bf16* __restrict__ Kh,
               const __bf16* __restrict__ VtG, __bf16* __restrict__ attn_out)
{
    __shared__ __bf16 Ks[2][4096];     // 64x64 K[k][d], swizzled
    __shared__ __bf16 Vt[2][4096];     // 64x64 V^T[d][k], swizzled
    __shared__ __bf16 Ps[8][16][72];   // per-wave P strip

    const int tid = threadIdx.x, wave = tid >> 6, lane = tid & 63;
    const int quad = lane >> 4, ln = lane & 15;
    const int p  = blockIdx.x >> 6;                       // pair id 0..7
    const int hb = blockIdx.x & 63, h = hb & 15, b = hb >> 4, bh = b * NH + h;

    // staging lane constants (XOR swizzle: LDS[row][c] = global[row][c^(row&7)])
    const int sr = lane >> 3, scl = (lane & 7) ^ sr;
    const size_t khead = (size_t)bh * S_ * 64;
    const int koff = (wave * 8 + sr) * 64 + scl * 8;      // chunk = wave
    const size_t vg = ((size_t)bh * 64 + wave * 8 + sr) * S_ + scl * 8;

    // fragment LDS element offsets (kt-invariant, swizzled)
    const int m7 = ln & 7;
    int ka[4][2];
#pragma unroll
    for (int nt = 0; nt < 4; nt++) {
        int row = nt * 16 + ln;
        ka[nt][0] = row * 64 + ((quad ^ m7) << 3);
        ka[nt][1] = row * 64 + (((quad + 4) ^ m7) << 3);
    }

    const int wl   = wave * 16 + ln;   // q-row local in [0,128)
    const int wl63 = wl & 63;          // diag-mask comparand (both wave groups)
    const bool hiw = wave >= 4;

    for (int hf = 0; hf < 2; hf++) {
        const int qt = hf ? p : (15 - p);
        const int Q0 = qt * 128, T0 = 2 * qt;

        // Q fragments: loop-invariant, direct from global (one subtile, K=64)
        const size_t qr = ((size_t)bh * S_ + Q0 + wl) * 64;
        const bf16x8_t qa0 = *reinterpret_cast<const bf16x8_t*>(&Qh[qr + quad * 8]);
        const bf16x8_t qa1 = *reinterpret_cast<const bf16x8_t*>(&Qh[qr + 32 + quad * 8]);

        floatx4_t o[4];
#pragma unroll
        for (int dt = 0; dt < 4; dt++) o[dt] = (floatx4_t){0.f, 0.f, 0.f, 0.f};

        // prologue: stage kt=0 into buf 0 (safe across halves — see header)
        GLOAD_LDS16(Kh  + khead + koff, &Ks[0][wave * 512]);
        GLOAD_LDS16(VtG + vg,           &Vt[0][wave * 512]);

        for (int kt = 0; kt <= T0 + 1; kt++) {
            const int buf = kt & 1;
            __syncthreads();                 // staging of buf done; prior reads of buf^1 done
            if (kt <= T0) {                  // prefetch kt+1 into the other buffer
                const int nb = buf ^ 1;
                GLOAD_LDS16(Kh  + khead + (size_t)(kt + 1) * 4096 + koff, &Ks[nb][wave * 512]);
                GLOAD_LDS16(VtG + vg + (kt + 1) * 64,                      &Vt[nb][wave * 512]);
            }

            // mode: 0 full, 1 diag, 2 skip (fully masked)
            const int rel = kt - T0;
            const int mode = (rel < 0) ? 0 : (rel == 0 ? (hiw ? 0 : 1) : (hiw ? 1 : 2));
            if (mode == 2) continue;

            // K fragments (A for S^T)
            bf16x8_t kf[4][2];
#pragma unroll
            for (int nt = 0; nt < 4; nt++) {
                kf[nt][0] = *reinterpret_cast<const bf16x8_t*>(&Ks[buf][ka[nt][0]]);
                kf[nt][1] = *reinterpret_cast<const bf16x8_t*>(&Ks[buf][ka[nt][1]]);
            }

            // ---- S^T = K * Q^T : C-layout row=k_l, col=q_l ----
            floatx4_t st[4];
            __builtin_amdgcn_s_setprio(1);
#pragma unroll
            for (int nt = 0; nt < 4; nt++) {
                floatx4_t acc = (floatx4_t){0.f, 0.f, 0.f, 0.f};
                acc = __builtin_amdgcn_mfma_f32_16x16x32_bf16(kf[nt][0], qa0, acc, 0, 0, 0);
                acc = __builtin_amdgcn_mfma_f32_16x16x32_bf16(kf[nt][1], qa1, acc, 0, 0, 0);
                st[nt] = acc;
            }
            __builtin_amdgcn_s_setprio(0);

            // ---- sigmoid -> P, packed b64 writes (4 consecutive k) ----
#pragma unroll
            for (int nt = 0; nt < 4; nt++) {
                bf16x4_t pk;
#pragma unroll
                for (int r = 0; r < 4; r++) {
                    float a = st[nt][r];
                    if (mode == 1) {
                        int kl = nt * 16 + quad * 4 + r;
                        a = (kl <= wl63) ? a : __builtin_inff();  // exp2(inf)->rcp->0
                    }
                    float pv = __builtin_amdgcn_rcpf(1.f + __builtin_amdgcn_exp2f(a));
                    pk[r] = (__bf16)pv;
                }
                *reinterpret_cast<bf16x4_t*>(&Ps[wave][ln][nt * 16 + quad * 4]) = pk;
            }

            // V fragments (read late to shorten live range)
            bf16x8_t vf[4][2];
#pragma unroll
            for (int dt = 0; dt < 4; dt++) {
                vf[dt][0] = *reinterpret_cast<const bf16x8_t*>(&Vt[buf][ka[dt][0]]);
                vf[dt][1] = *reinterpret_cast<const bf16x8_t*>(&Vt[buf][ka[dt][1]]);
            }

            // ---- O += P V ----
            const __bf16* prow = &Ps[wave][ln][quad * 8];
            bf16x8_t p0 = *reinterpret_cast<const bf16x8_t*>(prow);
            bf16x8_t p1 = *reinterpret_cast<const bf16x8_t*>(prow + 32);
            __builtin_amdgcn_s_setprio(1);
#pragma unroll
            for (int dt = 0; dt < 4; dt++) {
                o[dt] = __builtin_amdgcn_mfma_f32_16x16x32_bf16(p0, vf[dt][0], o[dt], 0, 0, 0);
                o[dt] = __builtin_amdgcn_mfma_f32_16x16x32_bf16(p1, vf[dt][1], o[dt], 0, 0, 0);
            }
            __builtin_amdgcn_s_setprio(0);
        }

        // write attn_out[b, q, h*64+d]  (C-layout: row=quad*4+reg, col=ln)
        const int qrow_g = b * S_ + Q0 + wave * 16 + quad * 4;
#pragma unroll
        for (int dt = 0; dt < 4; dt++) {
#pragma unroll
            for (int reg = 0; reg < 4; reg++) {
                attn_out[(size_t)(qrow_g + reg) * H + h * 64 + dt * 16 + ln] =
                    (__bf16)o[dt][reg];
            }
        }
    }
}

// ---------------------------------------------------------------------------
// LayerNorm over H + SiLU(U from Ug) gating -> bf16 gated.
// ---------------------------------------------------------------------------
__global__ __launch_bounds__(256)
void ln_gate_kernel(const __bf16* __restrict__ attn_out, const __bf16* __restrict__ Ug,
                    const float* __restrict__ ln_g, const float* __restrict__ ln_b,
                    __bf16* __restrict__ gated)
{
    const int row = blockIdx.x;
    const int tid = threadIdx.x;

    bf16x4_t vb = *reinterpret_cast<const bf16x4_t*>(&attn_out[(size_t)row * H + tid * 4]);
    float v0 = (float)vb[0], v1 = (float)vb[1], v2 = (float)vb[2], v3 = (float)vb[3];
    float s  = v0 + v1 + v2 + v3;
    float sq = v0 * v0 + v1 * v1 + v2 * v2 + v3 * v3;
#pragma unroll
    for (int off = 32; off > 0; off >>= 1) {
        s  += __shfl_down(s, off);
        sq += __shfl_down(sq, off);
    }
    __shared__ float ps[4], pq[4];
    int wave = tid >> 6, lane = tid & 63;
    if (lane == 0) { ps[wave] = s; pq[wave] = sq; }
    __syncthreads();
    float ts = ps[0] + ps[1] + ps[2] + ps[3];
    float tq = pq[0] + pq[1] + pq[2] + pq[3];
    float mu  = ts * (1.f / (float)H);
    float var = tq * (1.f / (float)H) - mu * mu;
    float rstd = rsqrtf(var + 1e-8f);

    bf16x4_t ub = *reinterpret_cast<const bf16x4_t*>(&Ug[(size_t)row * 1024 + tid * 4]);
    float4 g  = *reinterpret_cast<const float4*>(&ln_g[tid * 4]);
    float4 bb = *reinterpret_cast<const float4*>(&ln_b[tid * 4]);
    float u0 = (float)ub[0], u1 = (float)ub[1], u2 = (float)ub[2], u3 = (float)ub[3];
    bf16x4_t outv;
    outv[0] = (__bf16)(((v0 - mu) * rstd * g.x + bb.x) * (u0 / (1.f + __expf(-u0))));
    outv[1] = (__bf16)(((v1 - mu) * rstd * g.y + bb.y) * (u1 / (1.f + __expf(-u1))));
    outv[2] = (__bf16)(((v2 - mu) * rstd * g.z + bb.z) * (u2 / (1.f + __expf(-u2))));
    outv[3] = (__bf16)(((v3 - mu) * rstd * g.w + bb.w) * (u3 / (1.f + __expf(-u3))));
    *reinterpret_cast<bf16x4_t*>(&gated[(size_t)row * H + tid * 4]) = outv;
}

// ---------------------------------------------------------------------------
extern "C" void kernel_launch(void* const* d_in, const int* in_sizes, int n_in,
                              void* d_out, int out_size, void* d_ws, size_t ws_size,
                              hipStream_t stream)
{
    const float* x    = (const float*)d_in[0];
    // d_in[1] = attn_mask: structurally causal tril; causality computed from indices.
    const float* Wp   = (const float*)d_in[2];
    const float* bp   = (const float*)d_in[3];
    const float* ln_g = (const float*)d_in[4];
    const float* ln_b = (const float*)d_in[5];
    const float* Wt   = (const float*)d_in[6];
    const float* bt   = (const float*)d_in[7];
    float* out = (float*)d_out;

    char* ws = (char*)d_ws;
    const size_t MB = 1024 * 1024;
    __bf16* Ug    = (__bf16*)(ws);              // 16 MB
    __bf16* Vh    = (__bf16*)(ws + 16  * MB);   // 16 MB
    __bf16* Qh    = (__bf16*)(ws + 32  * MB);   // 16 MB
    __bf16* Kh    = (__bf16*)(ws + 48  * MB);   // 16 MB
    __bf16* attn  = (__bf16*)(ws + 64  * MB);   // 16 MB
    __bf16* gated = (__bf16*)(ws + 80  * MB);   // 16 MB
    __bf16* VtG   = (__bf16*)(ws + 96  * MB);   // 16 MB
    __bf16* Ax    = (__bf16*)(ws + 112 * MB);   // 16 MB
    __bf16* Wp_t  = (__bf16*)(ws + 128 * MB);   //  8 MB
    __bf16* Wt_t  = (__bf16*)(ws + 136 * MB);   //  2 MB

    prep_kernel<<<13312, 256, 0, stream>>>(x, Wp, Wt, Ax, Wp_t, Wt_t);

    dim3 g1(4096 / 256, ROWS / 256);
    gemm_proj<<<g1, 512, 0, stream>>>(Ax, Wp_t, bp, Ug, Vh, Qh, Kh);

    transpose_v<<<dim3(S_ / 64, B_ * NH), 256, 0, stream>>>(Vh, VtG);

    attn_mfma<<<8 * B_ * NH, 512, 0, stream>>>(Qh, Kh, VtG, attn);

    ln_gate_kernel<<<ROWS, 256, 0, stream>>>(attn, Ug, ln_g, ln_b, gated);

    dim3 g3(1024 / 128, ROWS / 128);
    gemm_out<<<g3, 256, 0, stream>>>(gated, Wt_t, bt, x, out, ROWS, 1024, 1024);
}

// Round 10
// 313.468 us; speedup vs baseline: 1.0468x; 1.0468x over previous
//
#include <hip/hip_runtime.h>
#include <math.h>

#define H 1024
#define NH 16
#define HD 64
#define B_ 4
#define S_ 2048
#define ROWS (B_*S_)   // 8192

// -0.125 * log2(e): folded into Qh so sigmoid(s*0.125) = rcp(1 + exp2(dot))
#define QSCALE (-0.1803368801111664f)
#define ROPE_C (9.210340371976184f / 32.0f)   // ln(10000)/32

typedef __bf16 bf16x2_t __attribute__((ext_vector_type(2)));
typedef __bf16 bf16x4_t __attribute__((ext_vector_type(4)));
typedef __bf16 bf16x8_t __attribute__((ext_vector_type(8)));
typedef float floatx4_t __attribute__((ext_vector_type(4)));
typedef float floatx16_t __attribute__((ext_vector_type(16)));

// async global->LDS, 16B per lane, dest = wave-uniform base + lane*16
#define GLOAD_LDS16(gp, lp)                                                        \
    __builtin_amdgcn_global_load_lds(                                              \
        (const __attribute__((address_space(1))) unsigned int*)(gp),               \
        (__attribute__((address_space(3))) unsigned int*)(lp), 16, 0, 0)

// ---------------------------------------------------------------------------
// Fused prep: x->bf16 copy, Wp transpose+cvt, Wt transpose+cvt (one dispatch)
// ---------------------------------------------------------------------------
__global__ __launch_bounds__(256)
void prep_kernel(const float* __restrict__ x, const float* __restrict__ Wp,
                 const float* __restrict__ Wt,
                 __bf16* __restrict__ Ax, __bf16* __restrict__ Wp_t,
                 __bf16* __restrict__ Wt_t)
{
    __shared__ __bf16 t[32][33];
    const int flat = blockIdx.x;
    const int tid = threadIdx.x;

    if (flat < 8192) {
        size_t i = (size_t)flat * 256 + tid;
        float4 v = *reinterpret_cast<const float4*>(&x[i * 4]);
        bf16x4_t w = { (__bf16)v.x, (__bf16)v.y, (__bf16)v.z, (__bf16)v.w };
        *reinterpret_cast<bf16x4_t*>(&Ax[i * 4]) = w;
        return;
    }
    const float* W; __bf16* Wo; int K, N, bn, bk;
    if (flat < 12288) {
        int id = flat - 8192;  W = Wp; Wo = Wp_t; K = 1024; N = 4096;
        bn = (id & 127) * 32;  bk = (id >> 7) * 32;
    } else {
        int id = flat - 12288; W = Wt; Wo = Wt_t; K = 1024; N = 1024;
        bn = (id & 31) * 32;   bk = (id >> 5) * 32;
    }
    const int tx = tid & 31, ty = tid >> 5;
#pragma unroll
    for (int i = 0; i < 4; i++) {
        int r = ty + i * 8;
        t[tx][r] = (__bf16)W[(size_t)(bk + r) * N + bn + tx];
    }
    __syncthreads();
#pragma unroll
    for (int i = 0; i < 4; i++) {
        int r = ty + i * 8;
        Wo[(size_t)(bn + r) * K + bk + tx] = t[r][tx];
    }
}

// ===========================================================================
// gemm_proj (R5 skeleton, R9: ONE barrier per phase): 256x256 tile, BK=64,
// 8 waves (2M x 4N), 8-phase schedule, 16x16x32 MFMA, default x-major grid.
// R8 lookahead reverted (null: MfmaUtil unchanged at 38%).
//
// R9 delta: the mid-phase barrier is deleted — phase is now
//   [ds_reads_p][stage_p][vmcnt(6)@p3/p7][MFMA_p][BARRIER]
// Legality audit (vs unchanged stage table + vmcnt placement):
//  - RAW/publication: p0-stage (A[1][1]) published at p3's vmcnt+BAR (vmcnt(6)
//    leaves only p1,p2,p3's 6 loads outstanding), first read p6 ✓;
//    p1..p4-stages published at p7's vmcnt+BAR, read next-iter p0/p2/p3 ✓;
//    p5..p7-stages published at next p3, read p4/p6 ✓.
//  - WAR: every slot restaged strictly after its last-read phase (B00: r p0/
//    s p1; A00: p0,p1/p2; B01: p2/p3; A01: p2,p3/p4; B10: p4/p5; A10:
//    p4,p5/p6; B11: p6/p7; A11: p6,p7/next p0). Reads are lgkm-drained by
//    their consuming MFMA before the phase barrier; the overwriting stage is
//    issued after that barrier by construction ✓.
// Stage table: p0 A[1][1]<-T+1 | p1 B[0][0]<-T+2 | p2 A[0][0]<-T+2
//              p3 B[0][1]<-T+2 | p4 A[0][1]<-T+2 | p5 B[1][0]<-T+3
//              p6 A[1][0]<-T+3 | p7 B[1][1]<-T+3   (T=2*iter)
// Swizzle: chunk c of row r at linear chunk c^((r>>1)&3) via inverse-permuted
// GLOBAL source (linear LDS dest). C/D 16x16: col=lane&15, row=(lane>>4)*4+reg.
// ===========================================================================

#define MIN15(x) ((x) < 15 ? (x) : 15)

#define STAGE_A(buf, h, tile) do { int _kb = (tile) * 64 + (h) * 32;               \
        char* _lb = lwA + ((buf) * 2 + (h)) * 16384;                               \
        GLOAD_LDS16(a_src0 + _kb, _lb);                                            \
        GLOAD_LDS16(a_src1 + _kb, _lb + 1024); } while (0)
#define STAGE_B(buf, h, tile) do { int _kb = (tile) * 64 + (h) * 32;               \
        char* _lb = lwB + ((buf) * 2 + (h)) * 16384;                               \
        GLOAD_LDS16(b_src0 + _kb, _lb);                                            \
        GLOAD_LDS16(b_src1 + _kb, _lb + 1024); } while (0)

__global__ __launch_bounds__(512, 2)
void gemm_proj(const __bf16* __restrict__ A, const __bf16* __restrict__ Bt,
               const float* __restrict__ bias,
               __bf16* __restrict__ Ug, __bf16* __restrict__ Vh,
               __bf16* __restrict__ Qh, __bf16* __restrict__ Kh)
{
    __shared__ __attribute__((aligned(16))) char smem[131072];

    const int tid  = threadIdx.x;
    const int wave = tid >> 6, lane = tid & 63;
    const int ln15 = lane & 15, q4 = lane >> 4;
    const int wm = wave & 1, wn = wave >> 1;
    const int m0 = blockIdx.y * 256, n0 = blockIdx.x * 256;

    // ---- staging constants: linear LDS dest, inverse-swizzled global src ----
    const int srow0 = wave * 32 + (lane >> 2);            // row for load p=0
    const int csrc  = (lane & 3) ^ ((lane >> 3) & 3);     // swizzled 16B chunk
    const __bf16* a_src0 = A  + (size_t)(m0 + srow0) * 1024 + csrc * 8;
    const __bf16* a_src1 = a_src0 + (size_t)16 * 1024;    // row +16 (load p=1)
    const __bf16* b_src0 = Bt + (size_t)(n0 + srow0) * 1024 + csrc * 8;
    const __bf16* b_src1 = b_src0 + (size_t)16 * 1024;
    char* lwA = smem + wave * 2048;                       // + slot*16384
    char* lwB = smem + 65536 + wave * 2048;

    // ---- fragment read offsets (swizzled) ----
    const int sl = (ln15 >> 1) & 3;
    const int a_lane = (wm * 128 + ln15) * 64 + ((q4 ^ sl) << 4);
    const int b_lane = (wn * 64  + ln15) * 64 + ((q4 ^ sl) << 4);

    floatx4_t acc[8][4];
#pragma unroll
    for (int i = 0; i < 8; i++)
#pragma unroll
        for (int j = 0; j < 4; j++) acc[i][j] = (floatx4_t){0.f, 0.f, 0.f, 0.f};

    // ---- prologue: T0 all 4 halves + T1 {Bk0, Ak0, Bk1}, FIFO order ----
    STAGE_B(0, 0, 0); STAGE_A(0, 0, 0); STAGE_B(0, 1, 0); STAGE_A(0, 1, 0);
    STAGE_B(1, 0, 1); STAGE_A(1, 0, 1); STAGE_B(1, 1, 1);
    asm volatile("s_waitcnt vmcnt(6)" ::: "memory");   // T0 landed
    __builtin_amdgcn_s_barrier();

    bf16x8_t bfr[4];

    for (int it = 0; it < 8; ++it) {
        const int T = 2 * it;
#pragma unroll
        for (int p = 0; p < 8; ++p) {
            const int buf = p >> 2, sub = p & 3, mh = sub & 1, kk = sub >> 1;
            const char* asl = smem + (buf * 2 + kk) * 16384;
            const char* bsl = smem + 65536 + (buf * 2 + kk) * 16384;

            // ds-loads for this phase (consumed by THIS phase's MFMA ->
            // lgkm-drained before the end barrier; required for 1-barrier WAR)
            if ((sub & 1) == 0) {
#pragma unroll
                for (int nf = 0; nf < 4; nf++)
                    bfr[nf] = *reinterpret_cast<const bf16x8_t*>(bsl + b_lane + nf * 1024);
            }
            bf16x8_t af[4];
#pragma unroll
            for (int mfi = 0; mfi < 4; mfi++)
                af[mfi] = *reinterpret_cast<const bf16x8_t*>(asl + a_lane + (mh * 4 + mfi) * 1024);

            // stage one half-tile (unchanged schedule)
            if      (p == 0) STAGE_A(1, 1, MIN15(T + 1));
            else if (p == 1) STAGE_B(0, 0, MIN15(T + 2));
            else if (p == 2) STAGE_A(0, 0, MIN15(T + 2));
            else if (p == 3) STAGE_B(0, 1, MIN15(T + 2));
            else if (p == 4) STAGE_A(0, 1, MIN15(T + 2));
            else if (p == 5) STAGE_B(1, 0, MIN15(T + 3));
            else if (p == 6) STAGE_A(1, 0, MIN15(T + 3));
            else             STAGE_B(1, 1, MIN15(T + 3));

            if (p == 3 || p == 7)
                asm volatile("s_waitcnt vmcnt(6)" ::: "memory");

            __builtin_amdgcn_s_setprio(1);
#pragma unroll
            for (int nf = 0; nf < 4; nf++)
#pragma unroll
                for (int mfi = 0; mfi < 4; mfi++)
                    acc[mh * 4 + mfi][nf] = __builtin_amdgcn_mfma_f32_16x16x32_bf16(
                        af[mfi], bfr[nf], acc[mh * 4 + mfi][nf], 0, 0, 0);
            __builtin_amdgcn_s_setprio(0);
            __builtin_amdgcn_s_barrier();      // single end-of-phase barrier
        }
    }
    asm volatile("s_waitcnt vmcnt(0)" ::: "memory");

    // ---- split epilogue (block-uniform region branch) ----
    const int colbase = n0 + wn * 64;
    float bv[4];
#pragma unroll
    for (int nf = 0; nf < 4; nf++) bv[nf] = bias[colbase + nf * 16 + ln15];

    const int rowb = m0 + wm * 128 + q4 * 4;   // + mf*16 + reg

    if (n0 < 1024) {
#pragma unroll
        for (int mf = 0; mf < 8; mf++)
#pragma unroll
            for (int nf = 0; nf < 4; nf++) {
                int col = colbase + nf * 16 + ln15;
#pragma unroll
                for (int reg = 0; reg < 4; reg++) {
                    int row = rowb + mf * 16 + reg;
                    Ug[(size_t)row * 1024 + col] = (__bf16)(acc[mf][nf][reg] + bv[nf]);
                }
            }
    } else if (n0 < 2048) {
        const int h = ((n0 - 1024) >> 6) + wn;    // wave spans one head
#pragma unroll
        for (int mf = 0; mf < 8; mf++)
#pragma unroll
            for (int reg = 0; reg < 4; reg++) {
                int row = rowb + mf * 16 + reg;
                int b = row >> 11, s = row & (S_ - 1);
                size_t orow = ((size_t)(b * NH + h) * S_ + s) * 64;
#pragma unroll
                for (int nf = 0; nf < 4; nf++)
                    Vh[orow + nf * 16 + ln15] = (__bf16)(acc[mf][nf][reg] + bv[nf]);
            }
    } else {
        const bool isQ = (n0 < 3072);
        const int h = ((n0 - (isQ ? 2048 : 3072)) >> 6) + wn;
        __bf16* dst = isQ ? Qh : Kh;
        const float sc = isQ ? QSCALE : 1.0f;
        // RoPE pair (d, d+32): d = nf*16+ln15 (nf=0,1), hi partner nf+2
        float inv[2];
        inv[0] = __expf(-(float)(ln15)      * ROPE_C);
        inv[1] = __expf(-(float)(16 + ln15) * ROPE_C);
#pragma unroll
        for (int mf = 0; mf < 8; mf++)
#pragma unroll
            for (int reg = 0; reg < 4; reg++) {
                int row = rowb + mf * 16 + reg;
                int b = row >> 11, s = row & (S_ - 1);
                size_t orow = ((size_t)(b * NH + h) * S_ + s) * 64;
#pragma unroll
                for (int nf = 0; nf < 2; nf++) {
                    float sn, cs;
                    __sincosf((float)s * inv[nf], &sn, &cs);
                    float lo = acc[mf][nf][reg]     + bv[nf];
                    float hi = acc[mf][nf + 2][reg] + bv[nf + 2];
                    int d = nf * 16 + ln15;
                    dst[orow + d]      = (__bf16)((lo * cs - hi * sn) * sc);
                    dst[orow + 32 + d] = (__bf16)((hi * cs + lo * sn) * sc);
                }
            }
    }
}

// ---------------------------------------------------------------------------
// out-proj GEMM: C = A @ Bt^T + bias + resid (fp32 out). 128x128, m97 struct.
// ---------------------------------------------------------------------------
__global__ __launch_bounds__(256)
void gemm_out(const __bf16* __restrict__ A, const __bf16* __restrict__ Bt,
              const float* __restrict__ bias, const float* __restrict__ resid,
              float* __restrict__ C, int M, int N, int K)
{
    __shared__ __bf16 As[128 * 32];
    __shared__ __bf16 Bs[128 * 32];

    const int tid  = threadIdx.x;
    const int wave = tid >> 6, lane = tid & 63;
    const int l31 = lane & 31, half = lane >> 5;
    const int wm = wave & 1, wn = wave >> 1;
    const int m0 = blockIdx.y * 128, n0 = blockIdx.x * 128;

    const int srow = lane >> 2;
    const int skc  = (((lane & 3) ^ ((srow >> 1) & 3)) * 8);

    const int fsw = (l31 >> 1) & 3;
    int aoff[2][2], boff[2][2];
#pragma unroll
    for (int mt = 0; mt < 2; mt++)
#pragma unroll
        for (int ks = 0; ks < 2; ks++) {
            int ra = wm * 64 + mt * 32 + l31;
            int rb = wn * 64 + mt * 32 + l31;
            int c = ks * 2 + half;
            aoff[mt][ks] = ra * 32 + ((c ^ fsw) * 8);
            boff[mt][ks] = rb * 32 + ((c ^ fsw) * 8);
        }

    floatx16_t acc[2][2];
#pragma unroll
    for (int i = 0; i < 2; i++)
#pragma unroll
        for (int j = 0; j < 2; j++) acc[i][j] = (floatx16_t)(0.f);

    for (int k0 = 0; k0 < K; k0 += 32) {
#pragma unroll
        for (int p = 0; p < 2; p++) {
            int i = wave * 2 + p;
            int rl = i * 16 + srow;
            GLOAD_LDS16(A  + (size_t)(m0 + rl) * K + k0 + skc, &As[i * 512]);
            GLOAD_LDS16(Bt + (size_t)(n0 + rl) * K + k0 + skc, &Bs[i * 512]);
        }
        __syncthreads();

        bf16x8_t af[2][2], bf[2][2];
#pragma unroll
        for (int mt = 0; mt < 2; mt++)
#pragma unroll
            for (int ks = 0; ks < 2; ks++) {
                af[mt][ks] = *reinterpret_cast<const bf16x8_t*>(&As[aoff[mt][ks]]);
                bf[mt][ks] = *reinterpret_cast<const bf16x8_t*>(&Bs[boff[mt][ks]]);
            }
#pragma unroll
        for (int ks = 0; ks < 2; ks++)
#pragma unroll
            for (int mt = 0; mt < 2; mt++)
#pragma unroll
                for (int nt = 0; nt < 2; nt++)
                    acc[mt][nt] = __builtin_amdgcn_mfma_f32_32x32x16_bf16(
                        af[mt][ks], bf[nt][ks], acc[mt][nt], 0, 0, 0);
        __syncthreads();
    }

#pragma unroll
    for (int mt = 0; mt < 2; mt++) {
#pragma unroll
        for (int nt = 0; nt < 2; nt++) {
            int col = n0 + wn * 64 + nt * 32 + l31;
            float bv = bias[col];
#pragma unroll
            for (int reg = 0; reg < 16; reg++) {
                int rowf = (reg & 3) + 8 * (reg >> 2) + 4 * half;
                int row = m0 + wm * 64 + mt * 32 + rowf;
                C[(size_t)row * N + col] = acc[mt][nt][reg] + bv + resid[(size_t)row * N + col];
            }
        }
    }
}

// ---------------------------------------------------------------------------
// V transpose: Vh[bh][s][64] -> VtG[bh][d][S]
// ---------------------------------------------------------------------------
__global__ __launch_bounds__(256)
void transpose_v(const __bf16* __restrict__ Vh, __bf16* __restrict__ VtG)
{
    const int tid = threadIdx.x;
    const int st = blockIdx.x, bh = blockIdx.y;
    const int s0 = st * 64;
    const int d = tid & 63, k16 = tid >> 6;
    __bf16 vals[16];
#pragma unroll
    for (int j = 0; j < 16; j++) {
        int k = s0 + k16 * 16 + j;
        vals[j] = Vh[((size_t)bh * S_ + k) * 64 + d];
    }
    size_t orow = ((size_t)(bh * 64 + d)) * S_ + s0 + k16 * 16;
    *reinterpret_cast<bf16x8_t*>(&VtG[orow])     = *reinterpret_cast<bf16x8_t*>(&vals[0]);
    *reinterpret_cast<bf16x8_t*>(&VtG[orow + 8]) = *reinterpret_cast<bf16x8_t*>(&vals[8]);
}

// ---------------------------------------------------------------------------
// Sigmoid attention, causal, bf16 MFMA. (R1 structure: 8 waves, one 16-row
// q-subtile per wave, qt-pairing for load balance; T5 setprio around QK/PV
// MFMA clusters.)
// ---------------------------------------------------------------------------
__global__ __launch_bounds__(512, 4)
void attn_mfma(const __bf16* __restrict__ Qh, const __bf16* __restrict__ Kh,
               const __bf16* __restrict__ VtG, __bf16* __restrict__ attn_out)
{
    __shared__ __bf16 Ks[2][4096];     // 64x64 K[k][d], swizzled
    __shared__ __bf16 Vt[2][4096];     // 64x64 V^T[d][k], swizzled
    __shared__ __bf16 Ps[8][16][72];   // per-wave P strip

    const int tid = threadIdx.x, wave = tid >> 6, lane = tid & 63;
    const int quad = lane >> 4, ln = lane & 15;
    const int p  = blockIdx.x >> 6;                       // pair id 0..7
    const int hb = blockIdx.x & 63, h = hb & 15, b = hb >> 4, bh = b * NH + h;

    // staging lane constants (XOR swizzle: LDS[row][c] = global[row][c^(row&7)])
    const int sr = lane >> 3, scl = (lane & 7) ^ sr;
    const size_t khead = (size_t)bh * S_ * 64;
    const int koff = (wave * 8 + sr) * 64 + scl * 8;      // chunk = wave
    const size_t vg = ((size_t)bh * 64 + wave * 8 + sr) * S_ + scl * 8;

    // fragment LDS element offsets (kt-invariant, swizzled)
    const int m7 = ln & 7;
    int ka[4][2];
#pragma unroll
    for (int nt = 0; nt < 4; nt++) {
        int row = nt * 16 + ln;
        ka[nt][0] = row * 64 + ((quad ^ m7) << 3);
        ka[nt][1] = row * 64 + (((quad + 4) ^ m7) << 3);
    }

    const int wl   = wave * 16 + ln;   // q-row local in [0,128)
    const int wl63 = wl & 63;          // diag-mask comparand (both wave groups)
    const bool hiw = wave >= 4;

    for (int hf = 0; hf < 2; hf++) {
        const int qt = hf ? p : (15 - p);
        const int Q0 = qt * 128, T0 = 2 * qt;

        // Q fragments: loop-invariant, direct from global (one subtile, K=64)
        const size_t qr = ((size_t)bh * S_ + Q0 + wl) * 64;
        const bf16x8_t qa0 = *reinterpret_cast<const bf16x8_t*>(&Qh[qr + quad * 8]);
        const bf16x8_t qa1 = *reinterpret_cast<const bf16x8_t*>(&Qh[qr + 32 + quad * 8]);

        floatx4_t o[4];
#pragma unroll
        for (int dt = 0; dt < 4; dt++) o[dt] = (floatx4_t){0.f, 0.f, 0.f, 0.f};

        // prologue: stage kt=0 into buf 0 (safe across halves — see header)
        GLOAD_LDS16(Kh  + khead + koff, &Ks[0][wave * 512]);
        GLOAD_LDS16(VtG + vg,           &Vt[0][wave * 512]);

        for (int kt = 0; kt <= T0 + 1; kt++) {
            const int buf = kt & 1;
            __syncthreads();                 // staging of buf done; prior reads of buf^1 done
            if (kt <= T0) {                  // prefetch kt+1 into the other buffer
                const int nb = buf ^ 1;
                GLOAD_LDS16(Kh  + khead + (size_t)(kt + 1) * 4096 + koff, &Ks[nb][wave * 512]);
                GLOAD_LDS16(VtG + vg + (kt + 1) * 64,                      &Vt[nb][wave * 512]);
            }

            // mode: 0 full, 1 diag, 2 skip (fully masked)
            const int rel = kt - T0;
            const int mode = (rel < 0) ? 0 : (rel == 0 ? (hiw ? 0 : 1) : (hiw ? 1 : 2));
            if (mode == 2) continue;

            // K fragments (A for S^T)
            bf16x8_t kf[4][2];
#pragma unroll
            for (int nt = 0; nt < 4; nt++) {
                kf[nt][0] = *reinterpret_cast<const bf16x8_t*>(&Ks[buf][ka[nt][0]]);
                kf[nt][1] = *reinterpret_cast<const bf16x8_t*>(&Ks[buf][ka[nt][1]]);
            }

            // ---- S^T = K * Q^T : C-layout row=k_l, col=q_l ----
            floatx4_t st[4];
            __builtin_amdgcn_s_setprio(1);
#pragma unroll
            for (int nt = 0; nt < 4; nt++) {
                floatx4_t acc = (floatx4_t){0.f, 0.f, 0.f, 0.f};
                acc = __builtin_amdgcn_mfma_f32_16x16x32_bf16(kf[nt][0], qa0, acc, 0, 0, 0);
                acc = __builtin_amdgcn_mfma_f32_16x16x32_bf16(kf[nt][1], qa1, acc, 0, 0, 0);
                st[nt] = acc;
            }
            __builtin_amdgcn_s_setprio(0);

            // ---- sigmoid -> P, packed b64 writes (4 consecutive k) ----
#pragma unroll
            for (int nt = 0; nt < 4; nt++) {
                bf16x4_t pk;
#pragma unroll
                for (int r = 0; r < 4; r++) {
                    float a = st[nt][r];
                    if (mode == 1) {
                        int kl = nt * 16 + quad * 4 + r;
                        a = (kl <= wl63) ? a : __builtin_inff();  // exp2(inf)->rcp->0
                    }
                    float pv = __builtin_amdgcn_rcpf(1.f + __builtin_amdgcn_exp2f(a));
                    pk[r] = (__bf16)pv;
                }
                *reinterpret_cast<bf16x4_t*>(&Ps[wave][ln][nt * 16 + quad * 4]) = pk;
            }

            // V fragments (read late to shorten live range)
            bf16x8_t vf[4][2];
#pragma unroll
            for (int dt = 0; dt < 4; dt++) {
                vf[dt][0] = *reinterpret_cast<const bf16x8_t*>(&Vt[buf][ka[dt][0]]);
                vf[dt][1] = *reinterpret_cast<const bf16x8_t*>(&Vt[buf][ka[dt][1]]);
            }

            // ---- O += P V ----
            const __bf16* prow = &Ps[wave][ln][quad * 8];
            bf16x8_t p0 = *reinterpret_cast<const bf16x8_t*>(prow);
            bf16x8_t p1 = *reinterpret_cast<const bf16x8_t*>(prow + 32);
            __builtin_amdgcn_s_setprio(1);
#pragma unroll
            for (int dt = 0; dt < 4; dt++) {
                o[dt] = __builtin_amdgcn_mfma_f32_16x16x32_bf16(p0, vf[dt][0], o[dt], 0, 0, 0);
                o[dt] = __builtin_amdgcn_mfma_f32_16x16x32_bf16(p1, vf[dt][1], o[dt], 0, 0, 0);
            }
            __builtin_amdgcn_s_setprio(0);
        }

        // write attn_out[b, q, h*64+d]  (C-layout: row=quad*4+reg, col=ln)
        const int qrow_g = b * S_ + Q0 + wave * 16 + quad * 4;
#pragma unroll
        for (int dt = 0; dt < 4; dt++) {
#pragma unroll
            for (int reg = 0; reg < 4; reg++) {
                attn_out[(size_t)(qrow_g + reg) * H + h * 64 + dt * 16 + ln] =
                    (__bf16)o[dt][reg];
            }
        }
    }
}

// ---------------------------------------------------------------------------
// LayerNorm over H + SiLU(U from Ug) gating -> bf16 gated.
// ---------------------------------------------------------------------------
__global__ __launch_bounds__(256)
void ln_gate_kernel(const __bf16* __restrict__ attn_out, const __bf16* __restrict__ Ug,
                    const float* __restrict__ ln_g, const float* __restrict__ ln_b,
                    __bf16* __restrict__ gated)
{
    const int row = blockIdx.x;
    const int tid = threadIdx.x;

    bf16x4_t vb = *reinterpret_cast<const bf16x4_t*>(&attn_out[(size_t)row * H + tid * 4]);
    float v0 = (float)vb[0], v1 = (float)vb[1], v2 = (float)vb[2], v3 = (float)vb[3];
    float s  = v0 + v1 + v2 + v3;
    float sq = v0 * v0 + v1 * v1 + v2 * v2 + v3 * v3;
#pragma unroll
    for (int off = 32; off > 0; off >>= 1) {
        s  += __shfl_down(s, off);
        sq += __shfl_down(sq, off);
    }
    __shared__ float ps[4], pq[4];
    int wave = tid >> 6, lane = tid & 63;
    if (lane == 0) { ps[wave] = s; pq[wave] = sq; }
    __syncthreads();
    float ts = ps[0] + ps[1] + ps[2] + ps[3];
    float tq = pq[0] + pq[1] + pq[2] + pq[3];
    float mu  = ts * (1.f / (float)H);
    float var = tq * (1.f / (float)H) - mu * mu;
    float rstd = rsqrtf(var + 1e-8f);

    bf16x4_t ub = *reinterpret_cast<const bf16x4_t*>(&Ug[(size_t)row * 1024 + tid * 4]);
    float4 g  = *reinterpret_cast<const float4*>(&ln_g[tid * 4]);
    float4 bb = *reinterpret_cast<const float4*>(&ln_b[tid * 4]);
    float u0 = (float)ub[0], u1 = (float)ub[1], u2 = (float)ub[2], u3 = (float)ub[3];
    bf16x4_t outv;
    outv[0] = (__bf16)(((v0 - mu) * rstd * g.x + bb.x) * (u0 / (1.f + __expf(-u0))));
    outv[1] = (__bf16)(((v1 - mu) * rstd * g.y + bb.y) * (u1 / (1.f + __expf(-u1))));
    outv[2] = (__bf16)(((v2 - mu) * rstd * g.z + bb.z) * (u2 / (1.f + __expf(-u2))));
    outv[3] = (__bf16)(((v3 - mu) * rstd * g.w + bb.w) * (u3 / (1.f + __expf(-u3))));
    *reinterpret_cast<bf16x4_t*>(&gated[(size_t)row * H + tid * 4]) = outv;
}

// ---------------------------------------------------------------------------
extern "C" void kernel_launch(void* const* d_in, const int* in_sizes, int n_in,
                              void* d_out, int out_size, void* d_ws, size_t ws_size,
                              hipStream_t stream)
{
    const float* x    = (const float*)d_in[0];
    // d_in[1] = attn_mask: structurally causal tril; causality computed from indices.
    const float* Wp   = (const float*)d_in[2];
    const float* bp   = (const float*)d_in[3];
    const float* ln_g = (const float*)d_in[4];
    const float* ln_b = (const float*)d_in[5];
    const float* Wt   = (const float*)d_in[6];
    const float* bt   = (const float*)d_in[7];
    float* out = (float*)d_out;

    char* ws = (char*)d_ws;
    const size_t MB = 1024 * 1024;
    __bf16* Ug    = (__bf16*)(ws);              // 16 MB
    __bf16* Vh    = (__bf16*)(ws + 16  * MB);   // 16 MB
    __bf16* Qh    = (__bf16*)(ws + 32  * MB);   // 16 MB
    __bf16* Kh    = (__bf16*)(ws + 48  * MB);   // 16 MB
    __bf16* attn  = (__bf16*)(ws + 64  * MB);   // 16 MB
    __bf16* gated = (__bf16*)(ws + 80  * MB);   // 16 MB
    __bf16* VtG   = (__bf16*)(ws + 96  * MB);   // 16 MB
    __bf16* Ax    = (__bf16*)(ws + 112 * MB);   // 16 MB
    __bf16* Wp_t  = (__bf16*)(ws + 128 * MB);   //  8 MB
    __bf16* Wt_t  = (__bf16*)(ws + 136 * MB);   //  2 MB

    prep_kernel<<<13312, 256, 0, stream>>>(x, Wp, Wt, Ax, Wp_t, Wt_t);

    dim3 g1(4096 / 256, ROWS / 256);
    gemm_proj<<<g1, 512, 0, stream>>>(Ax, Wp_t, bp, Ug, Vh, Qh, Kh);

    transpose_v<<<dim3(S_ / 64, B_ * NH), 256, 0, stream>>>(Vh, VtG);

    attn_mfma<<<8 * B_ * NH, 512, 0, stream>>>(Qh, Kh, VtG, attn);

    ln_gate_kernel<<<ROWS, 256, 0, stream>>>(attn, Ug, ln_g, ln_b, gated);

    dim3 g3(1024 / 128, ROWS / 128);
    gemm_out<<<g3, 256, 0, stream>>>(gated, Wt_t, bt, x, out, ROWS, 1024, 1024);
}